// Round 8
// baseline (229.881 us; speedup 1.0000x reference)
//
#include <hip/hip_runtime.h>
#include <math.h>

#define N_Q 4096
#define L_K 64
#define M_D 256

typedef float f32x16 __attribute__((ext_vector_type(16)));
typedef __bf16 b16x8 __attribute__((ext_vector_type(8)));
union F8 { uint4 u; unsigned short s[8]; b16x8 v; };

__device__ __forceinline__ unsigned short f2bf(float x) {
  unsigned u = __float_as_uint(x);
  return (unsigned short)((u + 0x7fffu + ((u >> 16) & 1u)) >> 16);  // RNE
}

// ---- k_prep: spec detect, out2 echo, per-n packed lists (no atomics), Wv^T, Wk frag image ----
__global__ __launch_bounds__(256) void k_prep(const unsigned char* __restrict__ raw,
                                              float* __restrict__ out2,
                                              const float* __restrict__ wv,
                                              float* __restrict__ wvt,
                                              const float* __restrict__ wk,
                                              unsigned short* __restrict__ wkf,
                                              const int* __restrict__ lin,
                                              int* __restrict__ pcnt,
                                              int* __restrict__ plin,
                                              unsigned char* __restrict__ pl) {
  __shared__ int pll_s[256];
  __shared__ unsigned char pls_s[256];
  __shared__ int pc_s[4];
  const int tid = threadIdx.x, lane = tid & 63;
  pll_s[tid] = 0;                  // default: slots >= cnt point at row 0, l = 0
  pls_s[tid] = 0;
  int v = 0;
  for (int i = tid; i < 4096; i += 256)
    if (i & 3) v |= raw[i];
  int f = __syncthreads_or(v);     // 1 = byte layout, 0 = int32 layout (barrier #1)
  const int gi = blockIdx.x * 256 + tid;          // covers N*L; wave = one n
  bool b = f ? (raw[gi] != 0) : (((const int*)raw)[gi] != 0);
  out2[gi] = b ? 1.0f : 0.0f;
  int li = lin[gi];
  unsigned long long mask = __ballot(b);
  if (b) {
    int rank = __popcll(mask & ((1ull << lane) - 1));
    pll_s[(tid & 192) + rank] = li;               // (tid>>6)*64 + rank
    pls_s[(tid & 192) + rank] = (unsigned char)lane;
  }
  if (lane == 0) pc_s[tid >> 6] = __popcll(mask);
  __syncthreads();
  plin[gi] = pll_s[tid];
  pl[gi] = pls_s[tid];
  if (tid < 4) pcnt[blockIdx.x * 4 + tid] = pc_s[tid];

  if (gi < 65536) {
    wvt[(gi & 255) * 256 + (gi >> 8)] = wv[gi];   // wvt[j][m] = wv[m][j]
    // A-frag image for mfma_32x32x16_bf16 (R4/R5-verified lane order), head-contiguous
    int oc = gi >> 8, k = gi & 255;
    int h = oc >> 5, c32o = oc & 31;
    int ks = k >> 4, kg2 = (k >> 3) & 1, j = k & 7;
    wkf[(((h * 16 + ks) << 6) + kg2 * 32 + c32o) * 8 + j] = f2bf(wk[gi]);
  }
}

// ---- k_main: persistent 512x512; wave w = head w, Wk A-frags in registers.
// Per n (grid-stride, 8 iters): G dbuf in LDS, ONE barrier, issue-early staging,
// in-register RoPE+softmax, V-agg via shfl broadcast -> agg bf16.
__global__ __launch_bounds__(512, 3) void k_main(
    const float* __restrict__ sv, const float* __restrict__ q,
    const unsigned short* __restrict__ wkf, const float* __restrict__ pos,
    const float* __restrict__ freqs, const int* __restrict__ pcnt,
    const int* __restrict__ plin, const unsigned char* __restrict__ pl,
    unsigned short* __restrict__ agg) {
  __shared__ __align__(16) char smem[65536];      // 2 x 32KB G tiles
  const int tid = threadIdx.x, lane = tid & 63, w = tid >> 6;
  const int c32 = lane & 31, kg = lane >> 5;
  const int ii = tid & 31, pr0 = tid >> 5;        // staging role: chunk ii, rows pr0+16k

  F8 afr[16];                                     // head w's Wk frags: 64 VGPRs, held
  #pragma unroll
  for (int ks = 0; ks < 16; ++ks)
    afr[ks].u = *(const uint4*)((const char*)wkf + ((((w * 16 + ks) << 6) + lane) << 4));

  auto loadrow = [&](int nb, int p, float4& f0, float4& f1) {
    const float* r = sv + (size_t)plin[nb * 64 + p] * 256 + ii * 8;
    f0 = *(const float4*)r;
    f1 = *(const float4*)(r + 4);
  };
  auto writerow = [&](char* gb, int p, const float4& f0, const float4& f1) {
    F8 pk;
    pk.s[0] = f2bf(f0.x); pk.s[1] = f2bf(f0.y); pk.s[2] = f2bf(f0.z); pk.s[3] = f2bf(f0.w);
    pk.s[4] = f2bf(f1.x); pk.s[5] = f2bf(f1.y); pk.s[6] = f2bf(f1.z); pk.s[7] = f2bf(f1.w);
    *(uint4*)(gb + p * 512 + ((ii ^ (p & 31)) << 4)) = pk.u;   // conflict-free XOR slot
  };

  int n = blockIdx.x;
  int cn = pcnt[n];
  {                                               // prologue: stage n into buf 0
    float4 a0, a1, b0, b1;
    loadrow(n, pr0, a0, a1); loadrow(n, pr0 + 16, b0, b1);
    writerow(smem, pr0, a0, a1); writerow(smem, pr0 + 16, b0, b1);
    if (cn > 32) {
      loadrow(n, pr0 + 32, a0, a1); loadrow(n, pr0 + 48, b0, b1);
      writerow(smem, pr0 + 32, a0, a1); writerow(smem, pr0 + 48, b0, b1);
    }
  }
  __syncthreads();

  int cur = 0;
  #pragma unroll 1
  for (int it = 0; it < 8; ++it) {
    const int nn = n + 512;
    const int cnn = (it < 7) ? pcnt[nn] : 0;
    char* gcur = smem + (cur << 15);
    char* gnxt = smem + ((cur ^ 1) << 15);

    // ---- issue next-G loads EARLY (land during MFMA/RoPE below) ----
    float4 A0, A1, B0, B1, C0, C1, D0, D1;
    const bool doA = it < 7;
    const bool doB = cnn > 32;
    if (doA) { loadrow(nn, pr0, A0, A1); loadrow(nn, pr0 + 16, B0, B1); }
    if (doB) { loadrow(nn, pr0 + 32, C0, C1); loadrow(nn, pr0 + 48, D0, D1); }

    // ---- RoPE meta (early issue) ----
    const int l0 = pl[n * 64 + c32];
    const int l1 = pl[n * 64 + 32 + c32];
    const float* pb0 = pos + ((size_t)n * 64 + l0) * 3;
    const float* pb1 = pos + ((size_t)n * 64 + l1) * 3;
    const float p00 = pb0[0], p01 = pb0[1], p02 = pb0[2];
    const float p10 = pb1[0], p11 = pb1[1], p12 = pb1[2];
    float2 qv[8];
    #pragma unroll
    for (int g = 0; g < 4; ++g)
      #pragma unroll
      for (int pr = 0; pr < 2; ++pr)
        qv[g * 2 + pr] = *(const float2*)(q + (size_t)n * 256 + w * 32 + g * 8 + kg * 4 + pr * 2);

    // ---- K-proj MFMA: acc cols = packed rows (R5-verified swapped layout) ----
    f32x16 acc0, acc1;
    #pragma unroll
    for (int r = 0; r < 16; ++r) { acc0[r] = 0.f; acc1[r] = 0.f; }
    #pragma unroll
    for (int ks = 0; ks < 16; ++ks) {
      const int sl = (((ks << 1) + kg) ^ c32) << 4;
      F8 bf0; bf0.u = *(const uint4*)(gcur + (c32 << 9) + sl);
      acc0 = __builtin_amdgcn_mfma_f32_32x32x16_bf16(afr[ks].v, bf0.v, acc0, 0, 0, 0);
    }
    if (cn > 32) {
      #pragma unroll
      for (int ks = 0; ks < 16; ++ks) {
        const int sl = (((ks << 1) + kg) ^ c32) << 4;
        F8 bf1; bf1.u = *(const uint4*)(gcur + ((32 + c32) << 9) + sl);
        acc1 = __builtin_amdgcn_mfma_f32_32x32x16_bf16(afr[ks].v, bf1.v, acc1, 0, 0, 0);
      }
    }

    // ---- in-register RoPE + q-dot ----
    const float* F = freqs + w * 16;
    float s0 = 0.f, s1 = 0.f;
    #pragma unroll
    for (int g = 0; g < 4; ++g) {
      #pragma unroll
      for (int pr = 0; pr < 2; ++pr) {
        const int jj = g * 4 + kg * 2 + pr;       // = d0>>1, d0 = g*8+kg*4+pr*2
        const int r = g * 4 + pr * 2;             // D row of reg r == d0
        const float fa = F[jj], fb = F[128 + jj], fc = F[256 + jj];
        const float2 qq = qv[g * 2 + pr];
        {
          float ang = p00 * fa + p01 * fb + p02 * fc;
          float sn, cs; __sincosf(ang, &sn, &cs);
          s0 += acc0[r] * (cs * qq.x + sn * qq.y) + acc0[r + 1] * (cs * qq.y - sn * qq.x);
        }
        if (cn > 32) {
          float ang = p10 * fa + p11 * fb + p12 * fc;
          float sn, cs; __sincosf(ang, &sn, &cs);
          s1 += acc1[r] * (cs * qq.x + sn * qq.y) + acc1[r + 1] * (cs * qq.y - sn * qq.x);
        }
      }
    }
    s0 += __shfl_xor(s0, 32); s0 *= 0.0625f;      // 1/sqrt(256)
    s1 += __shfl_xor(s1, 32); s1 *= 0.0625f;

    // ---- in-register masked softmax over packed rows ----
    const bool ok0 = c32 < cn, ok1 = (32 + c32) < cn;
    float mx = fmaxf(ok0 ? s0 : -3.4e38f, ok1 ? s1 : -3.4e38f);
    #pragma unroll
    for (int o = 16; o; o >>= 1) mx = fmaxf(mx, __shfl_xor(mx, o));
    float e0 = ok0 ? __expf(s0 - mx) : 0.f;
    float e1 = ok1 ? __expf(s1 - mx) : 0.f;
    float sm = e0 + e1;
    #pragma unroll
    for (int o = 16; o; o >>= 1) sm += __shfl_xor(sm, o);
    const float rs = (sm > 0.f) ? 1.0f / sm : 0.f;
    const float a0 = e0 * rs, a1 = e1 * rs;

    // ---- V-agg: ga[m-set] = sum_p attn[p] * G[p][m]; attn via shfl broadcast ----
    float ga0 = 0.f, ga1 = 0.f, ga2 = 0.f, ga3 = 0.f;
    for (int p = 0; p < cn; ++p) {
      const float av = __shfl((p < 32) ? a0 : a1, p & 31);
      const uint2 gv = *(const uint2*)(gcur + (p << 9) +
                         ((((lane >> 1) ^ (p & 31)) << 4) | ((lane & 1) << 3)));
      ga0 += av * __uint_as_float(gv.x << 16);
      ga1 += av * __uint_as_float(gv.x & 0xffff0000u);
      ga2 += av * __uint_as_float(gv.y << 16);
      ga3 += av * __uint_as_float(gv.y & 0xffff0000u);
    }
    ushort4 ov;
    ov.x = f2bf(ga0); ov.y = f2bf(ga1); ov.z = f2bf(ga2); ov.w = f2bf(ga3);
    *(ushort4*)(agg + (size_t)n * 2048 + w * 256 + lane * 4) = ov;

    // ---- write next G (loads issued ~2000 cycles ago), single barrier ----
    if (doA) { writerow(gnxt, pr0, A0, A1); writerow(gnxt, pr0 + 16, B0, B1); }
    if (doB) { writerow(gnxt, pr0 + 32, C0, C1); writerow(gnxt, pr0 + 48, D0, D1); }
    __syncthreads();
    cur ^= 1; n = nn; cn = cnn;
  }
}

// ---- k_out: out[n,m] = sum_j agg[n, h(m), j] * Wv[m, j]; 4 n per block ----
__global__ __launch_bounds__(256) void k_out(const unsigned short* __restrict__ agg,
                                             const float* __restrict__ wvt,
                                             float* __restrict__ out) {
  __shared__ float a_s[4][8][260];                // +4 pad
  const int tid = threadIdx.x;
  const int n0 = blockIdx.x * 4;
  #pragma unroll
  for (int it = 0; it < 4; ++it) {
    uint4 v = *(const uint4*)(agg + (size_t)(n0 + it) * 2048 + tid * 8);
    const unsigned short* sp = (const unsigned short*)&v;
    const int hh = tid >> 5, m0 = (tid & 31) * 8;
    #pragma unroll
    for (int k2 = 0; k2 < 8; ++k2)
      a_s[it][hh][m0 + k2] = __uint_as_float((unsigned)sp[k2] << 16);
  }
  __syncthreads();
  const int m = tid, h = m >> 5;
  float o0 = 0.f, o1 = 0.f, o2 = 0.f, o3 = 0.f;
  #pragma unroll 8
  for (int j = 0; j < 256; ++j) {
    float wvv = wvt[j * 256 + m];                 // coalesced, L2-hot
    o0 += a_s[0][h][j] * wvv;
    o1 += a_s[1][h][j] * wvv;
    o2 += a_s[2][h][j] * wvv;
    o3 += a_s[3][h][j] * wvv;
  }
  out[(n0 + 0) * 256 + m] = o0;
  out[(n0 + 1) * 256 + m] = o1;
  out[(n0 + 2) * 256 + m] = o2;
  out[(n0 + 3) * 256 + m] = o3;
}

extern "C" void kernel_launch(void* const* d_in, const int* in_sizes, int n_in,
                              void* d_out, int out_size, void* d_ws, size_t ws_size,
                              hipStream_t stream) {
  const float* sv  = (const float*)d_in[0];
  const int* lin   = (const int*)d_in[1];
  const unsigned char* raw = (const unsigned char*)d_in[2];
  const float* q   = (const float*)d_in[3];
  const float* wk  = (const float*)d_in[4];
  const float* wv  = (const float*)d_in[5];
  const float* pos = (const float*)d_in[6];
  const float* fq  = (const float*)d_in[7];
  float* out = (float*)d_out;
  char* ws = (char*)d_ws;

  float* wvt          = (float*)ws;                        // 262144
  unsigned short* wkf = (unsigned short*)(ws + 262144);    // 131072
  int* pcnt           = (int*)(ws + 393216);               // 16384
  int* plin           = (int*)(ws + 409600);               // 1048576
  unsigned char* pl   = (unsigned char*)(ws + 1458176);    // 262144
  unsigned short* agg = (unsigned short*)(ws + 1720320);   // 16777216 -> ~18.5MB

  k_prep<<<1024, 256, 0, stream>>>(raw, out + N_Q * M_D, wv, wvt, wk, wkf,
                                   lin, pcnt, plin, pl);
  k_main<<<512, 512, 0, stream>>>(sv, q, wkf, pos, fq, pcnt, plin, pl, agg);
  k_out <<<1024, 256, 0, stream>>>(agg, wvt, out);
}

// Round 9
// 123.038 us; speedup vs baseline: 1.8684x; 1.8684x over previous
//
#include <hip/hip_runtime.h>
#include <math.h>

#define N_Q 4096
#define L_K 64
#define M_D 256

typedef float f32x16 __attribute__((ext_vector_type(16)));
typedef __bf16 b16x8 __attribute__((ext_vector_type(8)));
union F8 { uint4 u; unsigned short s[8]; b16x8 v; };

__device__ __forceinline__ unsigned short f2bf(float x) {
  unsigned u = __float_as_uint(x);
  return (unsigned short)((u + 0x7fffu + ((u >> 16) & 1u)) >> 16);  // RNE
}

// ---- k_prep: spec detect, out2 echo, per-n packed lists (no atomics), Wv^T, Wk frag image ----
__global__ __launch_bounds__(256) void k_prep(const unsigned char* __restrict__ raw,
                                              float* __restrict__ out2,
                                              const float* __restrict__ wv,
                                              float* __restrict__ wvt,
                                              const float* __restrict__ wk,
                                              unsigned short* __restrict__ wkf,
                                              const int* __restrict__ lin,
                                              int* __restrict__ pcnt,
                                              int* __restrict__ plin,
                                              unsigned char* __restrict__ pl) {
  __shared__ int pll_s[256];
  __shared__ unsigned char pls_s[256];
  __shared__ int pc_s[4];
  const int tid = threadIdx.x, lane = tid & 63;
  pll_s[tid] = 0;
  pls_s[tid] = 0;
  int v = 0;
  for (int i = tid; i < 4096; i += 256)
    if (i & 3) v |= raw[i];
  int f = __syncthreads_or(v);     // 1 = byte layout, 0 = int32 layout
  const int gi = blockIdx.x * 256 + tid;          // covers N*L; wave = one n
  bool b = f ? (raw[gi] != 0) : (((const int*)raw)[gi] != 0);
  out2[gi] = b ? 1.0f : 0.0f;
  int li = lin[gi];
  unsigned long long mask = __ballot(b);
  if (b) {
    int rank = __popcll(mask & ((1ull << lane) - 1));
    pll_s[(tid & 192) + rank] = li;
    pls_s[(tid & 192) + rank] = (unsigned char)lane;
  }
  if (lane == 0) pc_s[tid >> 6] = __popcll(mask);
  __syncthreads();
  plin[gi] = pll_s[tid];
  pl[gi] = pls_s[tid];
  if (tid < 4) pcnt[blockIdx.x * 4 + tid] = pc_s[tid];

  if (gi < 65536) {
    wvt[(gi & 255) * 256 + (gi >> 8)] = wv[gi];   // wvt[j][m] = wv[m][j]
    // A-frag image for mfma_32x32x16_bf16 (R5-verified lane order)
    int oc = gi >> 8, k = gi & 255;
    int tt = oc >> 5, c32o = oc & 31;
    int ks = k >> 4, kg2 = (k >> 3) & 1, j = k & 7;
    wkf[(((tt * 16 + ks) << 6) + kg2 * 32 + c32o) * 8 + j] = f2bf(wk[gi]);
  }
}

// ---- k_scan: deterministic exclusive prefix over pcnt[4096] -> pbase; total at [4096] ----
__global__ __launch_bounds__(1024) void k_scan(const int* __restrict__ pcnt,
                                               int* __restrict__ pbase) {
  __shared__ int a[1024], b[1024];
  const int t = threadIdx.x;
  int c0 = pcnt[t * 4], c1 = pcnt[t * 4 + 1], c2 = pcnt[t * 4 + 2], c3 = pcnt[t * 4 + 3];
  a[t] = c0 + c1 + c2 + c3;
  __syncthreads();
  int* cur = a; int* alt = b;
  #pragma unroll
  for (int off = 1; off < 1024; off <<= 1) {
    int vv = cur[t] + ((t >= off) ? cur[t - off] : 0);
    alt[t] = vv;
    __syncthreads();
    int* tmp = cur; cur = alt; alt = tmp;
  }
  const int excl = (t > 0) ? cur[t - 1] : 0;
  pbase[t * 4]     = excl;
  pbase[t * 4 + 1] = excl + c0;
  pbase[t * 4 + 2] = excl + c0 + c1;
  pbase[t * 4 + 3] = excl + c0 + c1 + c2;
  if (t == 1023) pbase[4096] = cur[1023];
}

// ---- k_pack: scatter per-n lists into packed rowlinP / rinfoP (deterministic) ----
__global__ __launch_bounds__(256) void k_pack(const int* __restrict__ pcnt,
                                              const int* __restrict__ pbase,
                                              const int* __restrict__ plin,
                                              const unsigned char* __restrict__ pl,
                                              int* __restrict__ rowlinP,
                                              int* __restrict__ rinfoP) {
  const int gi = blockIdx.x * 256 + threadIdx.x;   // 262144
  const int n = gi >> 6, r = gi & 63;
  if (r < pcnt[n]) {
    const int p = pbase[n] + r;
    rowlinP[p] = plin[gi];
    rinfoP[p] = n * 64 + pl[gi];
  }
}

// ---- k_sgemm: dense K-proj GEMM over packed rows + register RoPE -> packed scores ----
// 2048 blocks x 512 thr (8 waves). Tile: 128 packed rows x 256 out.
// Wave (rg=w>>1, ch=w&1): rows rg*32..+31, heads ch*4..+3. acc 4 x f32x16.
__global__ __launch_bounds__(512, 4) void k_sgemm(
    const float* __restrict__ sv, const float* __restrict__ q,
    const unsigned short* __restrict__ wkf, const float* __restrict__ pos,
    const float* __restrict__ freqs, const int* __restrict__ pbase,
    const int* __restrict__ rowlinP, const int* __restrict__ rinfoP,
    float* __restrict__ scores_p) {
  const int total = pbase[4096];
  const int base = blockIdx.x * 128;
  if (base >= total) return;

  __shared__ __align__(16) char smem[65536];      // 128 rows x 512B bf16, XOR slots
  const int tid = threadIdx.x, lane = tid & 63, w = tid >> 6;
  const int c32 = lane & 31, kg = lane >> 5;
  const int rg = w >> 1, ch = w & 1;

  // ---- stage 128 rows coalesced: 32 lanes x one row, 2 x float4 each ----
  {
    const int rl = tid >> 5, ii = tid & 31;       // 16 rows per pass, chunk ii
    #pragma unroll
    for (int pp = 0; pp < 8; ++pp) {
      const int rloc = pp * 16 + rl;
      const int p = base + rloc;
      const int src = rowlinP[(p < total) ? p : (total - 1)];
      const float* rp = sv + (size_t)src * 256 + ii * 8;
      float4 f0 = *(const float4*)rp;
      float4 f1 = *(const float4*)(rp + 4);
      F8 pk;
      pk.s[0] = f2bf(f0.x); pk.s[1] = f2bf(f0.y); pk.s[2] = f2bf(f0.z); pk.s[3] = f2bf(f0.w);
      pk.s[4] = f2bf(f1.x); pk.s[5] = f2bf(f1.y); pk.s[6] = f2bf(f1.z); pk.s[7] = f2bf(f1.w);
      *(uint4*)(smem + rloc * 512 + ((ii ^ (rloc & 31)) << 4)) = pk.u;
    }
  }
  __syncthreads();

  f32x16 acc[4];
  #pragma unroll
  for (int t = 0; t < 4; ++t)
    #pragma unroll
    for (int r = 0; r < 16; ++r) acc[t][r] = 0.0f;

  const char* fbase = (const char*)wkf + ch * 65536 + lane * 16;
  F8 afc[4], afn[4];
  #pragma unroll
  for (int t = 0; t < 4; ++t) afc[t].u = *(const uint4*)(fbase + (t * 16) * 1024);

  #pragma unroll
  for (int ks = 0; ks < 16; ++ks) {
    if (ks < 15) {
      #pragma unroll
      for (int t = 0; t < 4; ++t)
        afn[t].u = *(const uint4*)(fbase + (t * 16 + ks + 1) * 1024);
    }
    F8 bf;                                        // B frag: shared across the 4 head-tiles
    bf.u = *(const uint4*)(smem + (rg * 32 + c32) * 512 + ((((ks << 1) + kg) ^ c32) << 4));
    #pragma unroll
    for (int t = 0; t < 4; ++t)
      acc[t] = __builtin_amdgcn_mfma_f32_32x32x16_bf16(afc[t].v, bf.v, acc[t], 0, 0, 0);
    #pragma unroll
    for (int t = 0; t < 4; ++t) afc[t] = afn[t];
  }

  // ---- in-register RoPE + q-dot (R5-verified D-layout); lane owns packed row p ----
  const int p = base + rg * 32 + c32;
  const bool pv = p < total;
  const int info = pv ? rinfoP[p] : 0;            // n*64 + l
  const int nn_ = info >> 6;
  const float* lp = pos + (size_t)info * 3;
  const float pp0 = lp[0], pp1 = lp[1], pp2 = lp[2];
  #pragma unroll
  for (int t = 0; t < 4; ++t) {
    const int h = ch * 4 + t;
    const float* qh = q + (size_t)nn_ * 256 + h * 32;
    const float* F = freqs + h * 16;
    float s = 0.f;
    #pragma unroll
    for (int g = 0; g < 4; ++g) {
      #pragma unroll
      for (int pr = 0; pr < 2; ++pr) {
        const int d0 = g * 8 + kg * 4 + pr * 2;
        const int jj = d0 >> 1;
        const int r = g * 4 + pr * 2;             // D row of reg r == d0
        float ke = acc[t][r], ko = acc[t][r + 1];
        float ang = pp0 * F[jj] + pp1 * F[128 + jj] + pp2 * F[256 + jj];
        float sn, cs;
        __sincosf(ang, &sn, &cs);
        float2 qq = *(const float2*)(qh + d0);
        s += ke * (cs * qq.x + sn * qq.y) + ko * (cs * qq.y - sn * qq.x);
      }
    }
    s += __shfl_xor(s, 32);
    if (kg == 0 && pv) scores_p[p * 8 + h] = s * 0.0625f;   // 1/sqrt(256)
  }
}

// ---- k_vagg: per-n softmax over packed scores + V-agg (coalesced rows) -> agg bf16 ----
__global__ __launch_bounds__(256, 8) void k_vagg(
    const float* __restrict__ sv, const int* __restrict__ pcnt,
    const int* __restrict__ pbase, const int* __restrict__ rowlinP,
    const float* __restrict__ scores_p, unsigned short* __restrict__ agg) {
  __shared__ float attn_s[64][8];
  __shared__ float sc_s[64][8];
  __shared__ int rl_s[64];
  const int tid = threadIdx.x, lane = tid & 63, w = tid >> 6;
  const int n = blockIdx.x;
  const int cnt = pcnt[n];
  if (cnt == 0) {
    #pragma unroll
    for (int h = 0; h < 8; ++h) agg[(size_t)n * 2048 + h * 256 + tid] = 0;
    return;
  }
  const int pb = pbase[n];
  if (tid < cnt) rl_s[tid] = rowlinP[pb + tid];
  for (int i = tid; i < cnt * 8; i += 256)
    sc_s[i >> 3][i & 7] = scores_p[(size_t)pb * 8 + i];
  __syncthreads();

  #pragma unroll
  for (int uu = 0; uu < 2; ++uu) {                // softmax: 8 heads, 2 per wave
    const int h = w * 2 + uu;
    const bool vl = lane < cnt;
    float v = vl ? sc_s[lane][h] : -__builtin_inff();
    float mx = v;
    #pragma unroll
    for (int o = 32; o; o >>= 1) mx = fmaxf(mx, __shfl_xor(mx, o));
    float e = vl ? __expf(v - mx) : 0.f;
    float sm = e;
    #pragma unroll
    for (int o = 32; o; o >>= 1) sm += __shfl_xor(sm, o);
    attn_s[lane][h] = e / sm;                     // cnt >= 1 -> sm > 0
  }
  __syncthreads();

  const int m = tid;
  float ga[8];
  #pragma unroll
  for (int h = 0; h < 8; ++h) ga[h] = 0.f;
  #pragma unroll 8
  for (int pL = 0; pL < cnt; ++pL) {
    const float gv = sv[(size_t)rl_s[pL] * 256 + m];        // 1KB coalesced row
    const float4* ap = (const float4*)&attn_s[pL][0];       // LDS broadcast
    float4 aA = ap[0], aB = ap[1];
    ga[0] += aA.x * gv; ga[1] += aA.y * gv; ga[2] += aA.z * gv; ga[3] += aA.w * gv;
    ga[4] += aB.x * gv; ga[5] += aB.y * gv; ga[6] += aB.z * gv; ga[7] += aB.w * gv;
  }
  #pragma unroll
  for (int h = 0; h < 8; ++h)
    agg[(size_t)n * 2048 + h * 256 + m] = f2bf(ga[h]);
}

// ---- k_out: out[n,m] = sum_j agg[n, h(m), j] * Wv[m, j]; 4 n per block ----
__global__ __launch_bounds__(256) void k_out(const unsigned short* __restrict__ agg,
                                             const float* __restrict__ wvt,
                                             float* __restrict__ out) {
  __shared__ float a_s[4][8][260];                // +4 pad
  const int tid = threadIdx.x;
  const int n0 = blockIdx.x * 4;
  #pragma unroll
  for (int it = 0; it < 4; ++it) {
    uint4 v = *(const uint4*)(agg + (size_t)(n0 + it) * 2048 + tid * 8);
    const unsigned short* sp = (const unsigned short*)&v;
    const int hh = tid >> 5, m0 = (tid & 31) * 8;
    #pragma unroll
    for (int k2 = 0; k2 < 8; ++k2)
      a_s[it][hh][m0 + k2] = __uint_as_float((unsigned)sp[k2] << 16);
  }
  __syncthreads();
  const int m = tid, h = m >> 5;
  float o0 = 0.f, o1 = 0.f, o2 = 0.f, o3 = 0.f;
  #pragma unroll 8
  for (int j = 0; j < 256; ++j) {
    float wvv = wvt[j * 256 + m];                 // coalesced, L2-hot
    o0 += a_s[0][h][j] * wvv;
    o1 += a_s[1][h][j] * wvv;
    o2 += a_s[2][h][j] * wvv;
    o3 += a_s[3][h][j] * wvv;
  }
  out[(n0 + 0) * 256 + m] = o0;
  out[(n0 + 1) * 256 + m] = o1;
  out[(n0 + 2) * 256 + m] = o2;
  out[(n0 + 3) * 256 + m] = o3;
}

extern "C" void kernel_launch(void* const* d_in, const int* in_sizes, int n_in,
                              void* d_out, int out_size, void* d_ws, size_t ws_size,
                              hipStream_t stream) {
  const float* sv  = (const float*)d_in[0];
  const int* lin   = (const int*)d_in[1];
  const unsigned char* raw = (const unsigned char*)d_in[2];
  const float* q   = (const float*)d_in[3];
  const float* wk  = (const float*)d_in[4];
  const float* wv  = (const float*)d_in[5];
  const float* pos = (const float*)d_in[6];
  const float* fq  = (const float*)d_in[7];
  float* out = (float*)d_out;
  char* ws = (char*)d_ws;

  float* wvt          = (float*)ws;                        // 262144
  unsigned short* wkf = (unsigned short*)(ws + 262144);    // 131072
  int* pcnt           = (int*)(ws + 393216);               // 16384
  int* pbase          = (int*)(ws + 409600);               // 16896 (4097 ints)
  int* plin           = (int*)(ws + 426496);               // 1048576
  unsigned char* pl   = (unsigned char*)(ws + 1475072);    // 262144
  int* rowlinP        = (int*)(ws + 1737216);              // 1048576
  int* rinfoP         = (int*)(ws + 2785792);              // 1048576
  float* scores_p     = (float*)(ws + 3834368);            // 8388608
  unsigned short* agg = (unsigned short*)(ws + 12222976);  // 16777216 -> ~29MB

  k_prep <<<1024, 256, 0, stream>>>(raw, out + N_Q * M_D, wv, wvt, wk, wkf,
                                    lin, pcnt, plin, pl);
  k_scan <<<1, 1024, 0, stream>>>(pcnt, pbase);
  k_pack <<<1024, 256, 0, stream>>>(pcnt, pbase, plin, pl, rowlinP, rinfoP);
  k_sgemm<<<2048, 512, 0, stream>>>(sv, q, wkf, pos, fq, pbase, rowlinP, rinfoP, scores_p);
  k_vagg <<<4096, 256, 0, stream>>>(sv, pcnt, pbase, rowlinP, scores_p, agg);
  k_out  <<<1024, 256, 0, stream>>>(agg, wvt, out);
}

// Round 10
// 108.788 us; speedup vs baseline: 2.1131x; 1.1310x over previous
//
#include <hip/hip_runtime.h>
#include <math.h>

#define N_Q 4096
#define L_K 64
#define M_D 256

typedef float f32x16 __attribute__((ext_vector_type(16)));
typedef __bf16 b16x8 __attribute__((ext_vector_type(8)));
union F8 { uint4 u; unsigned short s[8]; b16x8 v; };

__device__ __forceinline__ unsigned short f2bf(float x) {
  unsigned u = __float_as_uint(x);
  return (unsigned short)((u + 0x7fffu + ((u >> 16) & 1u)) >> 16);  // RNE
}

// ---- k_prep: spec detect, out2 echo, per-n packed lists (no atomics), Wv^T, Wk frag image ----
__global__ __launch_bounds__(256) void k_prep(const unsigned char* __restrict__ raw,
                                              float* __restrict__ out2,
                                              const float* __restrict__ wv,
                                              float* __restrict__ wvt,
                                              const float* __restrict__ wk,
                                              unsigned short* __restrict__ wkf,
                                              const int* __restrict__ lin,
                                              int* __restrict__ pcnt,
                                              int* __restrict__ plin,
                                              unsigned char* __restrict__ pl) {
  __shared__ int pll_s[256];
  __shared__ unsigned char pls_s[256];
  __shared__ int pc_s[4];
  const int tid = threadIdx.x, lane = tid & 63;
  pll_s[tid] = 0;                 // slots >= cnt default to row 0 / l 0
  pls_s[tid] = 0;
  int v = 0;
  for (int i = tid; i < 4096; i += 256)
    if (i & 3) v |= raw[i];
  int f = __syncthreads_or(v);    // 1 = byte layout, 0 = int32 layout
  const int gi = blockIdx.x * 256 + tid;          // covers N*L; wave = one n
  bool b = f ? (raw[gi] != 0) : (((const int*)raw)[gi] != 0);
  out2[gi] = b ? 1.0f : 0.0f;
  int li = lin[gi];
  unsigned long long mask = __ballot(b);
  if (b) {
    int rank = __popcll(mask & ((1ull << lane) - 1));
    pll_s[(tid & 192) + rank] = li;
    pls_s[(tid & 192) + rank] = (unsigned char)lane;
  }
  if (lane == 0) pc_s[tid >> 6] = __popcll(mask);
  __syncthreads();
  plin[gi] = pll_s[tid];
  pl[gi] = pls_s[tid];
  if (tid < 4) pcnt[blockIdx.x * 4 + tid] = pc_s[tid];

  if (gi < 65536) {
    wvt[(gi & 255) * 256 + (gi >> 8)] = wv[gi];   // wvt[j][m] = wv[m][j]
    // A-frag image for mfma_32x32x16_bf16 (R5/R9-verified lane order)
    int oc = gi >> 8, k = gi & 255;
    int tt = oc >> 5, c32o = oc & 31;
    int ks = k >> 4, kg2 = (k >> 3) & 1, j = k & 7;
    wkf[(((tt * 16 + ks) << 6) + kg2 * 32 + c32o) * 8 + j] = f2bf(wk[gi]);
  }
}

// ---- k_fused2: 2 n per block (rows <= 128). Stage G once -> K-proj MFMA + RoPE
//      -> in-block softmax -> V-agg from the SAME LDS G-tile -> agg bf16. ----
// 2048 blocks x 512 thr (8 waves). Wave (rt=w>>1, ch=w&1): row-tile rt, heads ch*4..+3.
#define SC_OFF  65536
#define AT_OFF  (SC_OFF + 4096)
#define LDS_SZ  (AT_OFF + 4096)          // 73728 B -> 2 blocks/CU

__global__ __launch_bounds__(512, 4) void k_fused2(
    const float* __restrict__ sv, const float* __restrict__ q,
    const unsigned short* __restrict__ wkf, const float* __restrict__ pos,
    const float* __restrict__ freqs, const int* __restrict__ pcnt,
    const int* __restrict__ plin, const unsigned char* __restrict__ pl,
    unsigned short* __restrict__ agg) {
  __shared__ __align__(16) char smem[LDS_SZ];
  float* sc_s   = (float*)(smem + SC_OFF);       // [128][8]
  float* attn_s = (float*)(smem + AT_OFF);       // [128][8]
  const int tid = threadIdx.x, lane = tid & 63, w = tid >> 6;
  const int c32 = lane & 31, kg = lane >> 5;
  const int rt = w >> 1, ch = w & 1;
  const int n0g = blockIdx.x * 2;
  const int cnt0 = pcnt[n0g], cnt1 = pcnt[n0g + 1];
  const int cpair = cnt0 + cnt1;

  if (cpair == 0) {                               // both n empty: zero agg
    #pragma unroll
    for (int i = tid; i < 1024; i += 512)
      *(ushort4*)(agg + (size_t)n0g * 2048 + i * 4) = ushort4{0, 0, 0, 0};
    return;
  }
  const int ct32 = (cpair + 31) & ~31;            // tile-padded row count
  const int ntiles = ct32 >> 5;

  // ---- stage rows coalesced: 16 rows/pass, clamped data in pad slots ----
  {
    const int r0 = tid >> 5, ii = tid & 31;
    #pragma unroll
    for (int pp = 0; pp < 8; ++pp) {
      const int rloc = pp * 16 + r0;
      if (rloc < ct32) {
        const int pe = (rloc < cpair) ? rloc : (cpair - 1);
        const int src = (pe < cnt0) ? plin[n0g * 64 + pe]
                                    : plin[(n0g + 1) * 64 + (pe - cnt0)];
        const float* rp = sv + (size_t)src * 256 + ii * 8;
        float4 f0 = *(const float4*)rp;
        float4 f1 = *(const float4*)(rp + 4);
        F8 pk;
        pk.s[0] = f2bf(f0.x); pk.s[1] = f2bf(f0.y); pk.s[2] = f2bf(f0.z); pk.s[3] = f2bf(f0.w);
        pk.s[4] = f2bf(f1.x); pk.s[5] = f2bf(f1.y); pk.s[6] = f2bf(f1.z); pk.s[7] = f2bf(f1.w);
        *(uint4*)(smem + rloc * 512 + ((ii ^ (rloc & 31)) << 4)) = pk.u;
      }
    }
  }
  __syncthreads();

  // ---- K-proj MFMA + in-register RoPE (R9-proven core) ----
  if (rt < ntiles) {
    f32x16 acc[4];
    #pragma unroll
    for (int t = 0; t < 4; ++t)
      #pragma unroll
      for (int r = 0; r < 16; ++r) acc[t][r] = 0.0f;

    const char* fbase = (const char*)wkf + ch * 65536 + lane * 16;
    F8 afc[4], afn[4];
    #pragma unroll
    for (int t = 0; t < 4; ++t) afc[t].u = *(const uint4*)(fbase + (t * 16) * 1024);

    #pragma unroll
    for (int ks = 0; ks < 16; ++ks) {
      if (ks < 15) {
        #pragma unroll
        for (int t = 0; t < 4; ++t)
          afn[t].u = *(const uint4*)(fbase + (t * 16 + ks + 1) * 1024);
      }
      F8 bf;
      bf.u = *(const uint4*)(smem + (rt * 32 + c32) * 512 + ((((ks << 1) + kg) ^ c32) << 4));
      #pragma unroll
      for (int t = 0; t < 4; ++t)
        acc[t] = __builtin_amdgcn_mfma_f32_32x32x16_bf16(afc[t].v, bf.v, acc[t], 0, 0, 0);
      #pragma unroll
      for (int t = 0; t < 4; ++t) afc[t] = afn[t];
    }

    const int p = rt * 32 + c32;                  // local packed row (lane-owned)
    const bool pv = p < cpair;
    const int pe = pv ? p : (cpair - 1);
    const int nl = (pe >= cnt0) ? 1 : 0;
    const int n_g = n0g + nl;
    const int l = pl[n_g * 64 + (pe - (nl ? cnt0 : 0))];
    const float* lp = pos + ((size_t)n_g * 64 + l) * 3;
    const float pp0 = lp[0], pp1 = lp[1], pp2 = lp[2];
    #pragma unroll
    for (int t = 0; t < 4; ++t) {
      const int h = ch * 4 + t;
      const float* qh = q + (size_t)n_g * 256 + h * 32;
      const float* F = freqs + h * 16;
      float s = 0.f;
      #pragma unroll
      for (int g = 0; g < 4; ++g) {
        #pragma unroll
        for (int pr = 0; pr < 2; ++pr) {
          const int d0 = g * 8 + kg * 4 + pr * 2;
          const int jj = d0 >> 1;
          const int r = g * 4 + pr * 2;           // D row of reg r == d0
          float ke = acc[t][r], ko = acc[t][r + 1];
          float ang = pp0 * F[jj] + pp1 * F[128 + jj] + pp2 * F[256 + jj];
          float sn, cs;
          __sincosf(ang, &sn, &cs);
          float2 qq = *(const float2*)(qh + d0);
          s += ke * (cs * qq.x + sn * qq.y) + ko * (cs * qq.y - sn * qq.x);
        }
      }
      s += __shfl_xor(s, 32);
      if (kg == 0 && pv) sc_s[p * 8 + h] = s * 0.0625f;   // 1/sqrt(256)
    }
  }
  __syncthreads();

  // ---- in-block softmax: 16 units (2 n x 8 h), 2 per wave ----
  #pragma unroll
  for (int uu = 0; uu < 2; ++uu) {
    const int unit = w * 2 + uu;
    const int nl = unit >> 3, h = unit & 7;
    const int start = nl ? cnt0 : 0;
    const int cn = nl ? cnt1 : cnt0;
    const bool vl = lane < cn;
    float v = vl ? sc_s[(start + lane) * 8 + h] : -__builtin_inff();
    float mx = v;
    #pragma unroll
    for (int o = 32; o; o >>= 1) mx = fmaxf(mx, __shfl_xor(mx, o));
    float e = vl ? __expf(v - mx) : 0.f;
    float sm = e;
    #pragma unroll
    for (int o = 32; o; o >>= 1) sm += __shfl_xor(sm, o);
    if (vl) attn_s[(start + lane) * 8 + h] = e / sm;    // cn>=1 when vl
  }
  __syncthreads();

  // ---- V-agg from the SAME G tile: thread (hh, m); conflict-free u16 reads ----
  const int m = tid & 255, hh = tid >> 8;
  const int start = hh ? cnt0 : 0;
  const int cn = hh ? cnt1 : cnt0;
  const int n_g = n0g + hh;
  float ga[8];
  #pragma unroll
  for (int h = 0; h < 8; ++h) ga[h] = 0.f;
  for (int p2 = 0; p2 < cn; ++p2) {
    const int prow = start + p2;
    unsigned short us = *(const unsigned short*)(smem + prow * 512 +
                        ((((m >> 3) ^ (prow & 31)) << 4) | ((m & 7) << 1)));
    float gv = __uint_as_float((unsigned)us << 16);
    const float4* ap = (const float4*)(attn_s + prow * 8);   // broadcast
    float4 aA = ap[0], aB = ap[1];
    ga[0] += aA.x * gv; ga[1] += aA.y * gv; ga[2] += aA.z * gv; ga[3] += aA.w * gv;
    ga[4] += aB.x * gv; ga[5] += aB.y * gv; ga[6] += aB.z * gv; ga[7] += aB.w * gv;
  }
  #pragma unroll
  for (int h = 0; h < 8; ++h)
    agg[(size_t)n_g * 2048 + h * 256 + m] = f2bf(ga[h]);
}

// ---- k_out: out[n,m] = sum_j agg[n, h(m), j] * Wv[m, j]; 4 n per block ----
__global__ __launch_bounds__(256) void k_out(const unsigned short* __restrict__ agg,
                                             const float* __restrict__ wvt,
                                             float* __restrict__ out) {
  __shared__ float a_s[4][8][260];                // +4 pad
  const int tid = threadIdx.x;
  const int n0 = blockIdx.x * 4;
  #pragma unroll
  for (int it = 0; it < 4; ++it) {
    uint4 v = *(const uint4*)(agg + (size_t)(n0 + it) * 2048 + tid * 8);
    const unsigned short* sp = (const unsigned short*)&v;
    const int hh = tid >> 5, m0 = (tid & 31) * 8;
    #pragma unroll
    for (int k2 = 0; k2 < 8; ++k2)
      a_s[it][hh][m0 + k2] = __uint_as_float((unsigned)sp[k2] << 16);
  }
  __syncthreads();
  const int m = tid, h = m >> 5;
  float o0 = 0.f, o1 = 0.f, o2 = 0.f, o3 = 0.f;
  #pragma unroll 8
  for (int j = 0; j < 256; ++j) {
    float wvv = wvt[j * 256 + m];                 // coalesced, L2-hot
    o0 += a_s[0][h][j] * wvv;
    o1 += a_s[1][h][j] * wvv;
    o2 += a_s[2][h][j] * wvv;
    o3 += a_s[3][h][j] * wvv;
  }
  out[(n0 + 0) * 256 + m] = o0;
  out[(n0 + 1) * 256 + m] = o1;
  out[(n0 + 2) * 256 + m] = o2;
  out[(n0 + 3) * 256 + m] = o3;
}

extern "C" void kernel_launch(void* const* d_in, const int* in_sizes, int n_in,
                              void* d_out, int out_size, void* d_ws, size_t ws_size,
                              hipStream_t stream) {
  const float* sv  = (const float*)d_in[0];
  const int* lin   = (const int*)d_in[1];
  const unsigned char* raw = (const unsigned char*)d_in[2];
  const float* q   = (const float*)d_in[3];
  const float* wk  = (const float*)d_in[4];
  const float* wv  = (const float*)d_in[5];
  const float* pos = (const float*)d_in[6];
  const float* fq  = (const float*)d_in[7];
  float* out = (float*)d_out;
  char* ws = (char*)d_ws;

  float* wvt          = (float*)ws;                        // 262144
  unsigned short* wkf = (unsigned short*)(ws + 262144);    // 131072
  int* pcnt           = (int*)(ws + 393216);               // 16384
  int* plin           = (int*)(ws + 409600);               // 1048576
  unsigned char* pl   = (unsigned char*)(ws + 1458176);    // 262144
  unsigned short* agg = (unsigned short*)(ws + 1720320);   // 16777216 -> ~18.5MB

  k_prep  <<<1024, 256, 0, stream>>>(raw, out + N_Q * M_D, wv, wvt, wk, wkf,
                                     lin, pcnt, plin, pl);
  k_fused2<<<2048, 512, 0, stream>>>(sv, q, wkf, pos, fq, pcnt, plin, pl, agg);
  k_out   <<<1024, 256, 0, stream>>>(agg, wvt, out);
}

// Round 11
// 107.768 us; speedup vs baseline: 2.1331x; 1.0095x over previous
//
#include <hip/hip_runtime.h>
#include <math.h>

#define N_Q 4096
#define L_K 64
#define M_D 256

typedef float f32x16 __attribute__((ext_vector_type(16)));
typedef __bf16 b16x8 __attribute__((ext_vector_type(8)));
union F8 { uint4 u; unsigned short s[8]; b16x8 v; };

__device__ __forceinline__ unsigned short f2bf(float x) {
  unsigned u = __float_as_uint(x);
  return (unsigned short)((u + 0x7fffu + ((u >> 16) & 1u)) >> 16);  // RNE
}

// ---- k_prep: spec detect, out2 echo, per-n packed lists (no atomics), Wv^T, Wk frag image ----
__global__ __launch_bounds__(256) void k_prep(const unsigned char* __restrict__ raw,
                                              float* __restrict__ out2,
                                              const float* __restrict__ wv,
                                              float* __restrict__ wvt,
                                              const float* __restrict__ wk,
                                              unsigned short* __restrict__ wkf,
                                              const int* __restrict__ lin,
                                              int* __restrict__ pcnt,
                                              int* __restrict__ plin,
                                              unsigned char* __restrict__ pl) {
  __shared__ int pll_s[256];
  __shared__ unsigned char pls_s[256];
  __shared__ int pc_s[4];
  const int tid = threadIdx.x, lane = tid & 63;
  pll_s[tid] = 0;                 // slots >= cnt default to row 0 / l 0
  pls_s[tid] = 0;
  int v = 0;
  for (int i = tid; i < 4096; i += 256)
    if (i & 3) v |= raw[i];
  int f = __syncthreads_or(v);    // 1 = byte layout, 0 = int32 layout
  const int gi = blockIdx.x * 256 + tid;          // covers N*L; wave = one n
  bool b = f ? (raw[gi] != 0) : (((const int*)raw)[gi] != 0);
  out2[gi] = b ? 1.0f : 0.0f;
  int li = lin[gi];
  unsigned long long mask = __ballot(b);
  if (b) {
    int rank = __popcll(mask & ((1ull << lane) - 1));
    pll_s[(tid & 192) + rank] = li;
    pls_s[(tid & 192) + rank] = (unsigned char)lane;
  }
  if (lane == 0) pc_s[tid >> 6] = __popcll(mask);
  __syncthreads();
  plin[gi] = pll_s[tid];
  pl[gi] = pls_s[tid];
  if (tid < 4) pcnt[blockIdx.x * 4 + tid] = pc_s[tid];

  if (gi < 65536) {
    wvt[(gi & 255) * 256 + (gi >> 8)] = wv[gi];   // wvt[j][m] = wv[m][j]
    // A-frag image for mfma_32x32x16_bf16 (R5/R9/R10-verified lane order)
    int oc = gi >> 8, k = gi & 255;
    int tt = oc >> 5, c32o = oc & 31;
    int ks = k >> 4, kg2 = (k >> 3) & 1, j = k & 7;
    wkf[(((tt * 16 + ks) << 6) + kg2 * 32 + c32o) * 8 + j] = f2bf(wk[gi]);
  }
}

// ---- k_fused3: ONE n per block (<=64 rows), 256 thr (4 waves), 36KB LDS -> 4 blocks/CU.
//      Stage G once -> K-proj MFMA + register RoPE -> softmax -> V-agg from same tile. ----
#define SC_OFF  32768
#define AT_OFF  (SC_OFF + 2048)
#define LDS_SZ  (AT_OFF + 2048)          // 36864 B -> 4 blocks/CU

__global__ __launch_bounds__(256, 4) void k_fused3(
    const float* __restrict__ sv, const float* __restrict__ q,
    const unsigned short* __restrict__ wkf, const float* __restrict__ pos,
    const float* __restrict__ freqs, const int* __restrict__ pcnt,
    const int* __restrict__ plin, const unsigned char* __restrict__ pl,
    unsigned short* __restrict__ agg) {
  __shared__ __align__(16) char smem[LDS_SZ];
  float* sc_s   = (float*)(smem + SC_OFF);       // [64][8]
  float* attn_s = (float*)(smem + AT_OFF);       // [64][8]
  const int tid = threadIdx.x, lane = tid & 63, w = tid >> 6;
  const int c32 = lane & 31, kg = lane >> 5;
  const int rt = w >> 1, ch = w & 1;
  const int n = blockIdx.x;
  const int cnt = pcnt[n];

  if (cnt == 0) {                                 // empty n: zero agg row, exit
    *(uint4*)((char*)agg + (size_t)n * 4096 + tid * 16) = uint4{0, 0, 0, 0};
    return;
  }
  const int ct32 = (cnt + 31) & ~31;              // 32 or 64
  const int ntiles = ct32 >> 5;

  // ---- stage <=64 rows coalesced: 8 rows/pass, clamped data in pad slots ----
  {
    const int r0 = tid >> 5, ii = tid & 31;
    #pragma unroll
    for (int pp = 0; pp < 8; ++pp) {
      const int rloc = pp * 8 + r0;
      if (rloc < ct32) {
        const int pe = (rloc < cnt) ? rloc : (cnt - 1);
        const float* rp = sv + (size_t)plin[n * 64 + pe] * 256 + ii * 8;
        float4 f0 = *(const float4*)rp;
        float4 f1 = *(const float4*)(rp + 4);
        F8 pk;
        pk.s[0] = f2bf(f0.x); pk.s[1] = f2bf(f0.y); pk.s[2] = f2bf(f0.z); pk.s[3] = f2bf(f0.w);
        pk.s[4] = f2bf(f1.x); pk.s[5] = f2bf(f1.y); pk.s[6] = f2bf(f1.z); pk.s[7] = f2bf(f1.w);
        *(uint4*)(smem + rloc * 512 + ((ii ^ (rloc & 31)) << 4)) = pk.u;
      }
    }
  }

  // ---- hoist RoPE meta (l, pos) so the 2-chain hides under staging/barrier ----
  const int p = rt * 32 + c32;                    // lane-owned packed row
  const bool pv = p < cnt;
  const int pe2 = pv ? p : (cnt - 1);
  const int l = pl[n * 64 + pe2];
  const float* lp = pos + ((size_t)n * 64 + l) * 3;
  const float pp0 = lp[0], pp1 = lp[1], pp2 = lp[2];

  __syncthreads();

  // ---- K-proj MFMA + in-register RoPE (R9/R10-proven core) ----
  if (rt < ntiles) {
    f32x16 acc[4];
    #pragma unroll
    for (int t = 0; t < 4; ++t)
      #pragma unroll
      for (int r = 0; r < 16; ++r) acc[t][r] = 0.0f;

    const char* fbase = (const char*)wkf + ch * 65536 + lane * 16;
    F8 afc[4], afn[4];
    #pragma unroll
    for (int t = 0; t < 4; ++t) afc[t].u = *(const uint4*)(fbase + (t * 16) * 1024);

    #pragma unroll
    for (int ks = 0; ks < 16; ++ks) {
      if (ks < 15) {
        #pragma unroll
        for (int t = 0; t < 4; ++t)
          afn[t].u = *(const uint4*)(fbase + (t * 16 + ks + 1) * 1024);
      }
      F8 bf;
      bf.u = *(const uint4*)(smem + (rt * 32 + c32) * 512 + ((((ks << 1) + kg) ^ c32) << 4));
      #pragma unroll
      for (int t = 0; t < 4; ++t)
        acc[t] = __builtin_amdgcn_mfma_f32_32x32x16_bf16(afc[t].v, bf.v, acc[t], 0, 0, 0);
      #pragma unroll
      for (int t = 0; t < 4; ++t) afc[t] = afn[t];
    }

    #pragma unroll
    for (int t = 0; t < 4; ++t) {
      const int h = ch * 4 + t;
      const float* qh = q + (size_t)n * 256 + h * 32;
      const float* F = freqs + h * 16;
      float s = 0.f;
      #pragma unroll
      for (int g = 0; g < 4; ++g) {
        #pragma unroll
        for (int pr = 0; pr < 2; ++pr) {
          const int d0 = g * 8 + kg * 4 + pr * 2;
          const int jj = d0 >> 1;
          const int r = g * 4 + pr * 2;           // D row of reg r == d0
          float ke = acc[t][r], ko = acc[t][r + 1];
          float ang = pp0 * F[jj] + pp1 * F[128 + jj] + pp2 * F[256 + jj];
          float sn = __sinf(ang), cs = __cosf(ang);   // native v_sin/v_cos path
          float2 qq = *(const float2*)(qh + d0);
          s += ke * (cs * qq.x + sn * qq.y) + ko * (cs * qq.y - sn * qq.x);
        }
      }
      s += __shfl_xor(s, 32);
      if (kg == 0 && pv) sc_s[p * 8 + h] = s * 0.0625f;   // 1/sqrt(256)
    }
  }
  __syncthreads();

  // ---- softmax: 8 heads, 2 per wave, over <=64 packed rows ----
  #pragma unroll
  for (int uu = 0; uu < 2; ++uu) {
    const int h = w * 2 + uu;
    const bool vl = lane < cnt;
    float v = vl ? sc_s[lane * 8 + h] : -__builtin_inff();
    float mx = v;
    #pragma unroll
    for (int o = 32; o; o >>= 1) mx = fmaxf(mx, __shfl_xor(mx, o));
    float e = vl ? __expf(v - mx) : 0.f;
    float sm = e;
    #pragma unroll
    for (int o = 32; o; o >>= 1) sm += __shfl_xor(sm, o);
    if (vl) attn_s[lane * 8 + h] = e / sm;        // cnt>=1 -> sm>0
  }
  __syncthreads();

  // ---- V-agg from the SAME G tile: thread = m; conflict-free u16 reads ----
  const int m = tid;
  float ga[8];
  #pragma unroll
  for (int h = 0; h < 8; ++h) ga[h] = 0.f;
  #pragma unroll 4
  for (int p2 = 0; p2 < cnt; ++p2) {
    unsigned short us = *(const unsigned short*)(smem + p2 * 512 +
                        ((((m >> 3) ^ (p2 & 31)) << 4) | ((m & 7) << 1)));
    float gv = __uint_as_float((unsigned)us << 16);
    const float4* ap = (const float4*)(attn_s + p2 * 8);   // broadcast
    float4 aA = ap[0], aB = ap[1];
    ga[0] += aA.x * gv; ga[1] += aA.y * gv; ga[2] += aA.z * gv; ga[3] += aA.w * gv;
    ga[4] += aB.x * gv; ga[5] += aB.y * gv; ga[6] += aB.z * gv; ga[7] += aB.w * gv;
  }
  #pragma unroll
  for (int h = 0; h < 8; ++h)
    agg[(size_t)n * 2048 + h * 256 + m] = f2bf(ga[h]);
}

// ---- k_out: out[n,m] = sum_j agg[n, h(m), j] * Wv[m, j]; 4 n per block ----
__global__ __launch_bounds__(256) void k_out(const unsigned short* __restrict__ agg,
                                             const float* __restrict__ wvt,
                                             float* __restrict__ out) {
  __shared__ float a_s[4][8][260];                // +4 pad
  const int tid = threadIdx.x;
  const int n0 = blockIdx.x * 4;
  #pragma unroll
  for (int it = 0; it < 4; ++it) {
    uint4 v = *(const uint4*)(agg + (size_t)(n0 + it) * 2048 + tid * 8);
    const unsigned short* sp = (const unsigned short*)&v;
    const int hh = tid >> 5, m0 = (tid & 31) * 8;
    #pragma unroll
    for (int k2 = 0; k2 < 8; ++k2)
      a_s[it][hh][m0 + k2] = __uint_as_float((unsigned)sp[k2] << 16);
  }
  __syncthreads();
  const int m = tid, h = m >> 5;
  float o0 = 0.f, o1 = 0.f, o2 = 0.f, o3 = 0.f;
  #pragma unroll 8
  for (int j = 0; j < 256; ++j) {
    float wvv = wvt[j * 256 + m];                 // coalesced, L2-hot
    o0 += a_s[0][h][j] * wvv;
    o1 += a_s[1][h][j] * wvv;
    o2 += a_s[2][h][j] * wvv;
    o3 += a_s[3][h][j] * wvv;
  }
  out[(n0 + 0) * 256 + m] = o0;
  out[(n0 + 1) * 256 + m] = o1;
  out[(n0 + 2) * 256 + m] = o2;
  out[(n0 + 3) * 256 + m] = o3;
}

extern "C" void kernel_launch(void* const* d_in, const int* in_sizes, int n_in,
                              void* d_out, int out_size, void* d_ws, size_t ws_size,
                              hipStream_t stream) {
  const float* sv  = (const float*)d_in[0];
  const int* lin   = (const int*)d_in[1];
  const unsigned char* raw = (const unsigned char*)d_in[2];
  const float* q   = (const float*)d_in[3];
  const float* wk  = (const float*)d_in[4];
  const float* wv  = (const float*)d_in[5];
  const float* pos = (const float*)d_in[6];
  const float* fq  = (const float*)d_in[7];
  float* out = (float*)d_out;
  char* ws = (char*)d_ws;

  float* wvt          = (float*)ws;                        // 262144
  unsigned short* wkf = (unsigned short*)(ws + 262144);    // 131072
  int* pcnt           = (int*)(ws + 393216);               // 16384
  int* plin           = (int*)(ws + 409600);               // 1048576
  unsigned char* pl   = (unsigned char*)(ws + 1458176);    // 262144
  unsigned short* agg = (unsigned short*)(ws + 1720320);   // 16777216 -> ~18.5MB

  k_prep  <<<1024, 256, 0, stream>>>(raw, out + N_Q * M_D, wv, wvt, wk, wkf,
                                     lin, pcnt, plin, pl);
  k_fused3<<<4096, 256, 0, stream>>>(sv, q, wkf, pos, fq, pcnt, plin, pl, agg);
  k_out   <<<1024, 256, 0, stream>>>(agg, wvt, out);
}